// Round 4
// baseline (694.327 us; speedup 1.0000x reference)
//
#include <hip/hip_runtime.h>
#include <hip/hip_cooperative_groups.h>

namespace cg = cooperative_groups;

typedef _Float16 f16;
typedef __attribute__((ext_vector_type(8))) _Float16 f16x8;
typedef __attribute__((ext_vector_type(2))) __fp16 hf16x2;   // native type of cvt_pkrtz
typedef __attribute__((ext_vector_type(4))) float f32x4;

constexpr int C_ = 4, L_ = 1000, K_ = 64, NOUT = 986, NPOS = 16 * 986; // 15776
constexpr int TPB  = 256;                       // 4 waves
constexpr int MTB  = 128;                       // positions per block (32/wave)
constexpr int NBLK = (NPOS + MTB - 1) / MTB;    // 124
constexpr int AST  = 104;                       // row stride (f16): 208 B, 16B-aligned
constexpr int ACT_EL  = MTB * AST;              // 13312 f16 (single in-place act buffer)
// LDS: act 26624 + bias(fp32) 1920 + head(fp32) 256 = 28800 B
constexpr size_t SMEM_BYTES = (size_t)ACT_EL * 2 + 480 * 4 + 64 * 4;

// ws: per layer l, per k: 96-row stride x AST cols fp16 W^T (row=out e, col=in d), zero-padded.
constexpr size_t WOFF[5]  = {0, 638976, 1277952, 1916928, 2555904};
constexpr int    WROWS[5] = {80, 96, 96, 80, 64};   // ceil16(DO)
constexpr int    DIv[5]   = {60, 72, 86, 86, 71};
constexpr int    DOv[5]   = {72, 86, 86, 71, 59};
// Precomputed L0 activation tiles appended after the weights (x-gather is 64x redundant
// across k). Stored in EXACT LDS layout (full 104-col rows incl. zero pads) so the main
// loop copies them with global_load_lds dwordx4.
constexpr size_t WTOT    = WOFF[4] + (size_t)K_ * 96 * AST;        // 3194880 f16
constexpr size_t ACT_WS  = WTOT;                                    // f16 index of tile region
constexpr size_t WS_NEED = (WTOT + (size_t)NBLK * ACT_EL) * 2;      // 9.69 MB

constexpr int NWUNIT = 5 * K_;          // 320 weight prep units (L,k)
constexpr int NPUNIT = NWUNIT + NBLK;   // + 124 act tiles = 444 phase-1 units

__device__ __forceinline__ float gelu_f(float x) {
    // tanh-form gelu as x*sigmoid(2z); validated R4/R9/R10 (absmax 3.9e-3).
    // R12: -2*log2(e) folded into the polynomial constants -> direct v_exp_f32.
    float x2 = x * x;
    float ei = x * __builtin_fmaf(-0.1029433270f, x2, -2.3022082020f);
    float e  = __builtin_amdgcn_exp2f(ei);       // = exp(-2z)
    return x * __builtin_amdgcn_rcpf(e + 1.0f);
}

// Prefetch ks=0 A-fragments of a layer into registers (24 VGPRs). Issued during the PREVIOUS
// layer's epilogue so the L2 latency is fully hidden at layer start.
template<int MT>
__device__ __forceinline__ void pre_a(const f16* __restrict__ wsrc, f16x8 (&ap)[6],
                                      int li, int q) {
#pragma unroll
    for (int mt = 0; mt < MT; mt++)
        ap[mt] = *(const f16x8*)(wsrc + (mt * 16 + li) * AST + q * 8);
}

// A = W^T from global (L2-resident; ks=0 from prefetched regs). B = act rows from wave-private
// LDS. Accumulator initialized with the bias (bias depends only on e = lane-fixed C rows).
template<int KSTEPS, int MT>
__device__ __forceinline__ void layer_mm_p(const f16* __restrict__ actw,
                                           const f16* __restrict__ wsrc,
                                           const f16x8 (&ap)[6],
                                           f32x4 (&acc)[MT][2],
                                           const float* __restrict__ bl, int li, int q) {
#pragma unroll
    for (int mt = 0; mt < MT; mt++) {
        f32x4 bb = *(const f32x4*)(bl + mt * 16 + q * 4);   // broadcast across li
#pragma unroll
        for (int nt = 0; nt < 2; nt++) acc[mt][nt] = bb;
    }
#pragma unroll
    for (int ks = 0; ks < KSTEPS; ks++) {
        const int koff = ks * 32 + q * 8;
        f16x8 a[MT], b[2];
#pragma unroll
        for (int mt = 0; mt < MT; mt++)
            a[mt] = (ks == 0) ? ap[mt]
                              : *(const f16x8*)(wsrc + (mt * 16 + li) * AST + koff);
#pragma unroll
        for (int nt = 0; nt < 2; nt++)
            b[nt] = *(const f16x8*)(actw + (nt * 16 + li) * AST + koff);   // ds_read_b128
#pragma unroll
        for (int mt = 0; mt < MT; mt++)
#pragma unroll
            for (int nt = 0; nt < 2; nt++)
                acc[mt][nt] = __builtin_amdgcn_mfma_f32_16x16x32_f16(a[mt], b[nt], acc[mt][nt], 0, 0, 0);
    }
}

// C/D: col(n=pos)=lane&15, row(m=e)=(lane>>4)*4+r -> lane owns 4 consecutive features of one
// position: gelu (bias already in acc) + pkrtz + one ds_write_b64. In-place act update: rows
// are wave-private, so NO barrier between layers.
template<int MT>
__device__ __forceinline__ void epilogue(f32x4 (&acc)[MT][2], f16* __restrict__ actw,
                                         int li, int q) {
#pragma unroll
    for (int mt = 0; mt < MT; mt++) {
        const int eb = mt * 16 + q * 4;
#pragma unroll
        for (int nt = 0; nt < 2; nt++) {
            union { hf16x2 h[2]; unsigned long long u; } pk;
            pk.h[0] = __builtin_amdgcn_cvt_pkrtz(gelu_f(acc[mt][nt][0]),
                                                 gelu_f(acc[mt][nt][1]));
            pk.h[1] = __builtin_amdgcn_cvt_pkrtz(gelu_f(acc[mt][nt][2]),
                                                 gelu_f(acc[mt][nt][3]));
            f16* dst = actw + (nt * 16 + li) * AST + eb;   // 8B aligned
            *(unsigned long long*)dst = pk.u;
        }
    }
}

// R13 weight prep (REVERTED from R14's uncoalesced direct form): coalesced global loads ->
// padded LDS transpose -> vector global stores. wl needs 86*87 f16 = 14964 B of scratch.
template<int L>
__device__ __forceinline__ void prep_one(const float* __restrict__ wsrc0, f16* __restrict__ ws,
                                         f16* __restrict__ wl, int k, int tid) {
    constexpr int DI = DIv[L], DO = DOv[L], RW = WROWS[L];
    const float* wsrc = wsrc0 + (size_t)k * DI * DO;
    constexpr int TOT = DI * DO;
    constexpr int NIT = (TOT + 255) / 256;
    float v[NIT];
#pragma unroll
    for (int it = 0; it < NIT; it++) {
        int i = tid + it * 256;
        v[it] = (i < TOT) ? wsrc[i] : 0.f;
    }
#pragma unroll
    for (int it = 0; it < NIT; it++) {
        int i = tid + it * 256;
        if (i < TOT) {
            int d = i / DO, e = i - d * DO;
            wl[d * 87 + e] = (f16)v[it];
        }
    }
    __syncthreads();
    f16* dst = ws + WOFF[L] + (size_t)k * 96 * AST;
    constexpr int CH = RW * 13;
    constexpr int NIT2 = (CH + 255) / 256;
#pragma unroll
    for (int it = 0; it < NIT2; it++) {
        int c = tid + it * 256;
        if (c < CH) {
            int e = c / 13, db = (c - e * 13) * 8;
            f16x8 vv;
#pragma unroll
            for (int j = 0; j < 8; j++) {
                int d = db + j;
                vv[j] = (e < DO && d < DI) ? wl[d * 87 + e] : (f16)0.f;
            }
            *(f16x8*)(dst + (size_t)c * 8) = vv;
        }
    }
}

// One mblk's L0 tile, chunked per 16B output (R14 form — validated). Cols 0..59 = x-window,
// 60..103 = zero (covers the K-pad AND cols 80..95 that K=96 loops read).
__device__ __forceinline__ void prep_act(const float* __restrict__ x, f16* __restrict__ dst0,
                                         int m, int tid) {
    if (m >= NBLK) return;
    f16* dst = dst0 + (size_t)m * ACT_EL;
    const int base = m * MTB;
    constexpr int CHK = MTB * 13;                // 1664 16B chunks per tile
    for (int i = tid; i < CHK; i += 256) {
        int r = i / 13, cc = (i - r * 13) * 8;
        int p = base + r; if (p > NPOS - 1) p = NPOS - 1;   // tail: duplicate last pos
        int b = p / NOUT, pos = p - b * NOUT;
        f16x8 vv;
#pragma unroll
        for (int j = 0; j < 8; j++) {
            int c = cc + j;
            float v = 0.f;
            if (c < 60) { int ch = c / 15, jj = c - ch * 15; v = x[(size_t)(b * C_ + ch) * L_ + pos + jj]; }
            vv[j] = (f16)v;
        }
        *(f16x8*)(dst + (size_t)r * AST + cc) = vv;
    }
}

// Fallback-path prep kernel (R13 grid structure, proven): grid (NBLK, 6).
__global__ __launch_bounds__(256) void prep_weights(
    const float* __restrict__ w0, const float* __restrict__ w1, const float* __restrict__ w2,
    const float* __restrict__ w3, const float* __restrict__ w4,
    const float* __restrict__ x, f16* __restrict__ ws) {
    __shared__ f16 wl[86 * 87];
    const int tid = threadIdx.x;
    if (blockIdx.y == 5) { prep_act(x, ws + ACT_WS, blockIdx.x, tid); return; }
    const int k = blockIdx.x;
    if (k >= K_) return;
    switch (blockIdx.y) {
        case 0: prep_one<0>(w0, ws, wl, k, tid); break;
        case 1: prep_one<1>(w1, ws, wl, k, tid); break;
        case 2: prep_one<2>(w2, ws, wl, k, tid); break;
        case 3: prep_one<3>(w3, ws, wl, k, tid); break;
        default: prep_one<4>(w4, ws, wl, k, tid); break;
    }
}

// Fallback main kernel — unchanged validated R13 form.
template<bool PRE>
__global__ __launch_bounds__(TPB, 4) void mlp_main(
    const float* __restrict__ x,
    const float* __restrict__ b0, const float* __restrict__ b1, const float* __restrict__ b2,
    const float* __restrict__ b3, const float* __restrict__ b4,
    const float* __restrict__ hw, const float* __restrict__ hb,
    const f16* __restrict__ ws, float* __restrict__ out) {
    extern __shared__ char smemraw[];
    f16*   act   = (f16*)smemraw;
    float* biasl = (float*)(act + ACT_EL);
    float* headl = biasl + 480;

    const int tid = threadIdx.x, k = blockIdx.x, mblk = blockIdx.y;
    const int wv = tid >> 6, lane = tid & 63, li = lane & 15, q = lane >> 4;
    const int base = mblk * MTB;
    f16* actw = act + (wv * 32) * AST;
    const f16* wk = ws + (size_t)k * 96 * AST;

    f16x8 ap[6];
    pre_a<5>(wk + WOFF[0], ap, li, q);

    for (int i = tid; i < 480; i += TPB) {
        int l = i / 96, e = i - l * 96;
        const float* bg = (l == 0) ? b0 : (l == 1) ? b1 : (l == 2) ? b2 : (l == 3) ? b3 : b4;
        int DO = (l == 0) ? 72 : (l == 1) ? 86 : (l == 2) ? 86 : (l == 3) ? 71 : 59;
        biasl[i] = (e < DO) ? bg[k * DO + e] : 0.f;
    }
    if (tid < 64) headl[tid] = (tid < 59) ? hw[tid] : 0.f;

    if constexpr (PRE) {
        const f16* src = ws + ACT_WS + (size_t)mblk * ACT_EL;
        for (int c = wv; c < 26; c += 4) {
            __builtin_amdgcn_global_load_lds(
                (const __attribute__((address_space(1))) void*)(src + c * 512 + lane * 8),
                (__attribute__((address_space(3))) void*)(act + c * 512), 16, 0, 0);
        }
    } else {
        const int b0i = base / NOUT;
        const int thr = (b0i + 1) * NOUT;
        for (int i = tid; i < 64 * MTB; i += TPB) {
            int d = i >> 7, r = i & (MTB - 1);
            int p = base + r; if (p > NPOS - 1) p = NPOS - 1;
            int b = (p >= thr) ? b0i + 1 : b0i;
            int pos = p - b * NOUT;
            float v = 0.f;
            if (d < 60) { int c = d / 15, j = d - c * 15; v = x[(size_t)(b * C_ + c) * L_ + pos + j]; }
            act[r * AST + d] = (f16)v;
        }
        for (int i = tid; i < MTB * 2; i += TPB) {
            int r = i >> 1, cc = (i & 1) << 3;
            *(f16x8*)(act + r * AST + 80 + cc) = f16x8{0,0,0,0,0,0,0,0};
        }
    }
    const float hb0 = hb[0];
    __syncthreads();

    f32x4 acc[6][2];
    f32x4 (&acc5)[5][2] = reinterpret_cast<f32x4 (&)[5][2]>(acc);

    layer_mm_p<2, 5>(actw, wk + WOFF[0], ap, acc5, biasl + 0 * 96, li, q);
    pre_a<6>(wk + WOFF[1], ap, li, q);
    epilogue<5>(acc5, actw, li, q);
    layer_mm_p<3, 6>(actw, wk + WOFF[1], ap, acc, biasl + 1 * 96, li, q);
    pre_a<6>(wk + WOFF[2], ap, li, q);
    epilogue<6>(acc, actw, li, q);
    layer_mm_p<3, 6>(actw, wk + WOFF[2], ap, acc, biasl + 2 * 96, li, q);
    pre_a<5>(wk + WOFF[3], ap, li, q);
    epilogue<6>(acc, actw, li, q);
    layer_mm_p<3, 5>(actw, wk + WOFF[3], ap, acc5, biasl + 3 * 96, li, q);
    pre_a<4>(wk + WOFF[4], ap, li, q);
    epilogue<5>(acc5, actw, li, q);

    f32x4 acc4[4][2];
    layer_mm_p<3, 4>(actw, wk + WOFF[4], ap, acc4, biasl + 4 * 96, li, q);
    float sum[2] = {0.f, 0.f};
#pragma unroll
    for (int mt = 0; mt < 4; mt++) {
        const int eb = mt * 16 + q * 4;
        f32x4 hh = *(const f32x4*)(headl + eb);
#pragma unroll
        for (int nt = 0; nt < 2; nt++) {
#pragma unroll
            for (int r = 0; r < 4; r++)
                sum[nt] += gelu_f(acc4[mt][nt][r]) * hh[r];
        }
    }
#pragma unroll
    for (int nt = 0; nt < 2; nt++) {
        float s = sum[nt];
        s += __shfl_xor(s, 16);
        s += __shfl_xor(s, 32);
        s += hb0;
        if (lane < 16) {
            int p = base + wv * 32 + nt * 16 + lane;
            if (p < NPOS) {
                int b = p / NOUT, pos = p - b * NOUT;
                out[((size_t)(b * K_ + k)) * NOUT + pos] = s;
            }
        }
    }
}

// R15: cooperative fused kernel. Phase 1 distributes the 444 prep units over the co-resident
// grid (weight transposes reuse the act LDS as scratch); grid.sync(); phase 2 runs persistent
// blocks with k = bid&63 FIXED (preserves the k%8-per-XCD L2 mapping, biases loaded once),
// looping m over tiles with per-item act re-staging. Pipeline math identical to mlp_main.
__global__ __launch_bounds__(TPB, 4) void mlp_coop(
    const float* __restrict__ x,
    const float* __restrict__ w0, const float* __restrict__ w1, const float* __restrict__ w2,
    const float* __restrict__ w3, const float* __restrict__ w4,
    const float* __restrict__ b0, const float* __restrict__ b1, const float* __restrict__ b2,
    const float* __restrict__ b3, const float* __restrict__ b4,
    const float* __restrict__ hw, const float* __restrict__ hb,
    f16* __restrict__ ws, float* __restrict__ out) {
    extern __shared__ char smemraw[];
    f16*   act   = (f16*)smemraw;                 // [128 pos][AST]; phase-1 scratch
    float* biasl = (float*)(act + ACT_EL);
    float* headl = biasl + 480;

    const int tid = threadIdx.x, bid = blockIdx.x, gsz = gridDim.x;

    // ---- phase 1: prep ws (weights 0..319, act tiles 320..443) ----
    for (int u = bid; u < NPUNIT; u += gsz) {
        if (u < NWUNIT) {
            const int L = u >> 6, k2 = u & 63;
            f16* wl = act;                        // 14964 B scratch < ACT_EL*2, clear of biasl
            switch (L) {
                case 0: prep_one<0>(w0, ws, wl, k2, tid); break;
                case 1: prep_one<1>(w1, ws, wl, k2, tid); break;
                case 2: prep_one<2>(w2, ws, wl, k2, tid); break;
                case 3: prep_one<3>(w3, ws, wl, k2, tid); break;
                default: prep_one<4>(w4, ws, wl, k2, tid); break;
            }
        } else {
            prep_act(x, ws + ACT_WS, u - NWUNIT, tid);
        }
        __syncthreads();                          // wl reuse safety if looping
    }

    // per-block constants (k fixed): biases + head into LDS; latency hides under grid.sync
    const int k = bid & 63;
    for (int i = tid; i < 480; i += TPB) {
        int l = i / 96, e = i - l * 96;
        const float* bg = (l == 0) ? b0 : (l == 1) ? b1 : (l == 2) ? b2 : (l == 3) ? b3 : b4;
        int DO = (l == 0) ? 72 : (l == 1) ? 86 : (l == 2) ? 86 : (l == 3) ? 71 : 59;
        biasl[i] = (e < DO) ? bg[k * DO + e] : 0.f;
    }
    if (tid < 64) headl[tid] = (tid < 59) ? hw[tid] : 0.f;
    const float hb0 = hb[0];

    cg::this_grid().sync();                       // producer->consumer, device-scope fence

    // ---- phase 2: persistent item loop over m tiles ----
    const int m0 = bid >> 6, mstep = gsz >> 6;    // gsz is a multiple of 64
    const int wv = tid >> 6, lane = tid & 63, li = lane & 15, q = lane >> 4;
    f16* actw = act + (wv * 32) * AST;
    const f16* wk = ws + (size_t)k * 96 * AST;

    f16x8 ap[6];
    pre_a<5>(wk + WOFF[0], ap, li, q);            // weights ready only after grid.sync

    for (int m = m0; m < NBLK; m += mstep) {
        __syncthreads();                          // prev item done reading act / bias ready
        const f16* src = ws + ACT_WS + (size_t)m * ACT_EL;
        for (int c = wv; c < 26; c += 4) {
            __builtin_amdgcn_global_load_lds(
                (const __attribute__((address_space(1))) void*)(src + c * 512 + lane * 8),
                (__attribute__((address_space(3))) void*)(act + c * 512), 16, 0, 0);
        }
        __syncthreads();                          // drains vmcnt: staged tile visible

        f32x4 acc[6][2];
        f32x4 (&acc5)[5][2] = reinterpret_cast<f32x4 (&)[5][2]>(acc);

        layer_mm_p<2, 5>(actw, wk + WOFF[0], ap, acc5, biasl + 0 * 96, li, q);  // L0
        pre_a<6>(wk + WOFF[1], ap, li, q);
        epilogue<5>(acc5, actw, li, q);
        layer_mm_p<3, 6>(actw, wk + WOFF[1], ap, acc, biasl + 1 * 96, li, q);   // L1
        pre_a<6>(wk + WOFF[2], ap, li, q);
        epilogue<6>(acc, actw, li, q);
        layer_mm_p<3, 6>(actw, wk + WOFF[2], ap, acc, biasl + 2 * 96, li, q);   // L2
        pre_a<5>(wk + WOFF[3], ap, li, q);
        epilogue<6>(acc, actw, li, q);
        layer_mm_p<3, 5>(actw, wk + WOFF[3], ap, acc5, biasl + 3 * 96, li, q);  // L3
        pre_a<4>(wk + WOFF[4], ap, li, q);
        epilogue<5>(acc5, actw, li, q);

        f32x4 acc4[4][2];
        layer_mm_p<3, 4>(actw, wk + WOFF[4], ap, acc4, biasl + 4 * 96, li, q);  // L4
        pre_a<5>(wk + WOFF[0], ap, li, q);        // re-arm W0 for next item (hides under head)

        const int base = m * MTB;
        float sum[2] = {0.f, 0.f};
#pragma unroll
        for (int mt = 0; mt < 4; mt++) {
            const int eb = mt * 16 + q * 4;
            f32x4 hh = *(const f32x4*)(headl + eb);
#pragma unroll
            for (int nt = 0; nt < 2; nt++) {
#pragma unroll
                for (int r = 0; r < 4; r++)
                    sum[nt] += gelu_f(acc4[mt][nt][r]) * hh[r];
            }
        }
#pragma unroll
        for (int nt = 0; nt < 2; nt++) {
            float s = sum[nt];
            s += __shfl_xor(s, 16);
            s += __shfl_xor(s, 32);
            s += hb0;
            if (lane < 16) {
                int p = base + wv * 32 + nt * 16 + lane;
                if (p < NPOS) {
                    int b = p / NOUT, pos = p - b * NOUT;
                    out[((size_t)(b * K_ + k)) * NOUT + pos] = s;
                }
            }
        }
    }
}

extern "C" void kernel_launch(void* const* d_in, const int* in_sizes, int n_in,
                              void* d_out, int out_size, void* d_ws, size_t ws_size,
                              hipStream_t stream) {
    const float* x  = (const float*)d_in[0];
    const float* w0 = (const float*)d_in[1];  const float* b0 = (const float*)d_in[2];
    const float* w1 = (const float*)d_in[3];  const float* b1 = (const float*)d_in[4];
    const float* w2 = (const float*)d_in[5];  const float* b2 = (const float*)d_in[6];
    const float* w3 = (const float*)d_in[7];  const float* b3 = (const float*)d_in[8];
    const float* w4 = (const float*)d_in[9];  const float* b4 = (const float*)d_in[10];
    const float* hw = (const float*)d_in[11]; const float* hb = (const float*)d_in[12];
    float* out = (float*)d_out;
    f16* ws = (f16*)d_ws;

    int dev = 0; (void)hipGetDevice(&dev);
    int ncu = 0;
    hipError_t ea = hipDeviceGetAttribute(&ncu, hipDeviceAttributeMultiprocessorCount, dev);
    int nb = 0;
    hipError_t eb = hipOccupancyMaxActiveBlocksPerMultiprocessor(
        &nb, (const void*)mlp_coop, TPB, SMEM_BYTES);

    bool coop = (ea == hipSuccess) && (eb == hipSuccess) &&
                (ws_size >= WS_NEED) && (ncu > 0) && (nb > 0) && ((size_t)nb * ncu >= 64);

    if (coop) {
        if (nb > 4) nb = 4;                        // 4/CU: best item-count balance (124 = 16*7+12)
        int grid = (nb * ncu / 64) * 64;           // multiple of 64 for the k = bid&63 mapping
        (void)hipFuncSetAttribute((const void*)mlp_coop,
                                  hipFuncAttributeMaxDynamicSharedMemorySize, (int)SMEM_BYTES);
        void* args[] = {(void*)&x,
                        (void*)&w0, (void*)&w1, (void*)&w2, (void*)&w3, (void*)&w4,
                        (void*)&b0, (void*)&b1, (void*)&b2, (void*)&b3, (void*)&b4,
                        (void*)&hw, (void*)&hb, (void*)&ws, (void*)&out};
        (void)hipLaunchCooperativeKernel((const void*)mlp_coop, dim3(grid), dim3(TPB),
                                         args, (unsigned)SMEM_BYTES, stream);
    } else if (ws_size >= WS_NEED) {
        (void)hipFuncSetAttribute((const void*)mlp_main<true>,
                                  hipFuncAttributeMaxDynamicSharedMemorySize, (int)SMEM_BYTES);
        prep_weights<<<dim3(NBLK, 6), 256, 0, stream>>>(w0, w1, w2, w3, w4, x, ws);
        mlp_main<true><<<dim3(K_, NBLK), TPB, SMEM_BYTES, stream>>>(
            x, b0, b1, b2, b3, b4, hw, hb, ws, out);
    } else {
        (void)hipFuncSetAttribute((const void*)mlp_main<false>,
                                  hipFuncAttributeMaxDynamicSharedMemorySize, (int)SMEM_BYTES);
        prep_weights<<<dim3(K_, 5), 256, 0, stream>>>(w0, w1, w2, w3, w4, x, ws);
        mlp_main<false><<<dim3(K_, NBLK), TPB, SMEM_BYTES, stream>>>(
            x, b0, b1, b2, b3, b4, hw, hb, ws, out);
    }
}

// Round 5
// 253.573 us; speedup vs baseline: 2.7382x; 2.7382x over previous
//
#include <hip/hip_runtime.h>

typedef _Float16 f16;
typedef __attribute__((ext_vector_type(8))) _Float16 f16x8;
typedef __attribute__((ext_vector_type(2))) __fp16 hf16x2;   // native type of cvt_pkrtz
typedef __attribute__((ext_vector_type(4))) float f32x4;

constexpr int C_ = 4, L_ = 1000, K_ = 64, NOUT = 986, NPOS = 16 * 986; // 15776
constexpr int TPB  = 256;                       // 4 waves
constexpr int MTB  = 128;                       // positions per block (32/wave)
constexpr int NBLK = (NPOS + MTB - 1) / MTB;    // 124
constexpr int AST  = 104;                       // row stride (f16): 208 B, 16B-aligned
constexpr int ACT_EL  = MTB * AST;              // 13312 f16 (single in-place act buffer)
// LDS: act 26624 + bias(fp32) 1920 + head(fp32) 256 = 28800 B; 5 blocks/CU = 144000 <= 160K
constexpr size_t SMEM_BYTES = (size_t)ACT_EL * 2 + 480 * 4 + 64 * 4;

// ws: per layer l, per k: 96-row stride x AST cols fp16 W^T (row=out e, col=in d), zero-padded.
constexpr size_t WOFF[5]  = {0, 638976, 1277952, 1916928, 2555904};
constexpr int    WROWS[5] = {80, 96, 96, 80, 64};   // ceil16(DO)
constexpr int    DIv[5]   = {60, 72, 86, 86, 71};
constexpr int    DOv[5]   = {72, 86, 86, 71, 59};
// Precomputed L0 activation tiles appended after the weights (x-gather is 64x redundant
// across k). Stored in EXACT LDS layout (full 104-col rows incl. zero pads) so the main
// loop copies them with global_load_lds dwordx4.
constexpr size_t WTOT    = WOFF[4] + (size_t)K_ * 96 * AST;        // 3194880 f16
constexpr size_t ACT_WS  = WTOT;                                    // f16 index of tile region
constexpr size_t WS_NEED = (WTOT + (size_t)NBLK * ACT_EL) * 2;      // 9.69 MB

// R16 prep decomposition: every unit split in two for 2x block parallelism (prep was
// latency-bound at 1.7 blocks/CU). Weight unit u<WUNITS: L=u>>7, k=(u>>1)&63, half=u&1.
constexpr int WUNITS = 5 * K_ * 2;   // 640
constexpr int AUNITS = NBLK * 2;     // 248

__device__ __forceinline__ float gelu_f(float x) {
    // tanh-form gelu as x*sigmoid(2z); validated R4/R9/R10 (absmax 3.9e-3).
    // R12: -2*log2(e) folded into the polynomial constants -> direct v_exp_f32.
    float x2 = x * x;
    float ei = x * __builtin_fmaf(-0.1029433270f, x2, -2.3022082020f);
    float e  = __builtin_amdgcn_exp2f(ei);       // = exp(-2z)
    return x * __builtin_amdgcn_rcpf(e + 1.0f);
}

// Prefetch ks=0 A-fragments of a layer into registers (24 VGPRs). Issued during the PREVIOUS
// layer's epilogue so the L2 latency is fully hidden at layer start.
// (R12 full-panel variant refuted: panel spilled to AGPR side -> 3 waves/SIMD, no gain.
//  R15 coop fusion refuted: persistent blocks destroy dispatch-order L2 locality.)
template<int MT>
__device__ __forceinline__ void pre_a(const f16* __restrict__ wsrc, f16x8 (&ap)[6],
                                      int li, int q) {
#pragma unroll
    for (int mt = 0; mt < MT; mt++)
        ap[mt] = *(const f16x8*)(wsrc + (mt * 16 + li) * AST + q * 8);
}

// A = W^T from global (L2-resident; ks=0 from prefetched regs). B = act rows from wave-private
// LDS. Accumulator initialized with the bias (bias depends only on e = lane-fixed C rows).
template<int KSTEPS, int MT>
__device__ __forceinline__ void layer_mm_p(const f16* __restrict__ actw,
                                           const f16* __restrict__ wsrc,
                                           const f16x8 (&ap)[6],
                                           f32x4 (&acc)[MT][2],
                                           const float* __restrict__ bl, int li, int q) {
#pragma unroll
    for (int mt = 0; mt < MT; mt++) {
        f32x4 bb = *(const f32x4*)(bl + mt * 16 + q * 4);   // broadcast across li
#pragma unroll
        for (int nt = 0; nt < 2; nt++) acc[mt][nt] = bb;
    }
#pragma unroll
    for (int ks = 0; ks < KSTEPS; ks++) {
        const int koff = ks * 32 + q * 8;
        f16x8 a[MT], b[2];
#pragma unroll
        for (int mt = 0; mt < MT; mt++)
            a[mt] = (ks == 0) ? ap[mt]
                              : *(const f16x8*)(wsrc + (mt * 16 + li) * AST + koff);
#pragma unroll
        for (int nt = 0; nt < 2; nt++)
            b[nt] = *(const f16x8*)(actw + (nt * 16 + li) * AST + koff);   // ds_read_b128
#pragma unroll
        for (int mt = 0; mt < MT; mt++)
#pragma unroll
            for (int nt = 0; nt < 2; nt++)
                acc[mt][nt] = __builtin_amdgcn_mfma_f32_16x16x32_f16(a[mt], b[nt], acc[mt][nt], 0, 0, 0);
    }
}

// C/D: col(n=pos)=lane&15, row(m=e)=(lane>>4)*4+r -> lane owns 4 consecutive features of one
// position: gelu (bias already in acc) + pkrtz + one ds_write_b64. In-place act update: rows
// are wave-private, so NO barrier between layers.
template<int MT>
__device__ __forceinline__ void epilogue(f32x4 (&acc)[MT][2], f16* __restrict__ actw,
                                         int li, int q) {
#pragma unroll
    for (int mt = 0; mt < MT; mt++) {
        const int eb = mt * 16 + q * 4;
#pragma unroll
        for (int nt = 0; nt < 2; nt++) {
            union { hf16x2 h[2]; unsigned long long u; } pk;
            pk.h[0] = __builtin_amdgcn_cvt_pkrtz(gelu_f(acc[mt][nt][0]),
                                                 gelu_f(acc[mt][nt][1]));
            pk.h[1] = __builtin_amdgcn_cvt_pkrtz(gelu_f(acc[mt][nt][2]),
                                                 gelu_f(acc[mt][nt][3]));
            f16* dst = actw + (nt * 16 + li) * AST + eb;   // 8B aligned
            *(unsigned long long*)dst = pk.u;
        }
    }
}

// R16 weight prep: R13's proven coalesced-load -> padded-LDS-transpose -> vector store, but
// each (L,k) panel split across 2 blocks by e-halves (phase 1 duplicated: w reads are small
// and L2/HBM-cheap; phase 2 halved -> shorter critical path). Output bytes identical to R13.
template<int L>
__device__ __forceinline__ void prep_one_half(const float* __restrict__ wsrc0,
                                              f16* __restrict__ ws, f16* __restrict__ wl,
                                              int k, int h, int tid) {
    constexpr int DI = DIv[L], DO = DOv[L], RW = WROWS[L];
    const float* wsrc = wsrc0 + (size_t)k * DI * DO;
    constexpr int TOT = DI * DO;
    constexpr int NIT = (TOT + 255) / 256;
    float v[NIT];
#pragma unroll
    for (int it = 0; it < NIT; it++) {
        int i = tid + it * 256;
        v[it] = (i < TOT) ? wsrc[i] : 0.f;
    }
#pragma unroll
    for (int it = 0; it < NIT; it++) {
        int i = tid + it * 256;
        if (i < TOT) {
            int d = i / DO, e = i - d * DO;
            wl[d * 87 + e] = (f16)v[it];
        }
    }
    __syncthreads();
    f16* dst = ws + WOFF[L] + (size_t)k * 96 * AST;
    constexpr int HCH = (RW / 2) * 13;           // 16B chunks in this half
    constexpr int NIT2 = (HCH + 255) / 256;
#pragma unroll
    for (int it = 0; it < NIT2; it++) {
        int c0 = tid + it * 256;
        if (c0 < HCH) {
            int c = h * HCH + c0;
            int e = c / 13, db = (c - e * 13) * 8;
            f16x8 vv;
#pragma unroll
            for (int j = 0; j < 8; j++) {
                int d = db + j;
                vv[j] = (e < DO && d < DI) ? wl[d * 87 + e] : (f16)0.f;
            }
            *(f16x8*)(dst + (size_t)c * 8) = vv;
        }
    }
}

// Half of one mblk's L0 tile (chunked per 16B output). Cols 0..59 = x-window, 60..103 = zero
// (covers the K-pad AND cols 80..95 that K=96 loops read but MT=5 epilogues never write).
__device__ __forceinline__ void prep_act_half(const float* __restrict__ x,
                                              f16* __restrict__ dst0, int m, int h, int tid) {
    if (m >= NBLK) return;
    f16* dst = dst0 + (size_t)m * ACT_EL;
    const int base = m * MTB;
    constexpr int HCHK = MTB * 13 / 2;           // 832 chunks per half
    for (int i0 = tid; i0 < HCHK; i0 += 256) {
        int i = h * HCHK + i0;
        int r = i / 13, cc = (i - r * 13) * 8;
        int p = base + r; if (p > NPOS - 1) p = NPOS - 1;   // tail: duplicate last pos
        int b = p / NOUT, pos = p - b * NOUT;
        f16x8 vv;
#pragma unroll
        for (int j = 0; j < 8; j++) {
            int c = cc + j;
            float v = 0.f;
            if (c < 60) { int ch = c / 15, jj = c - ch * 15; v = x[(size_t)(b * C_ + ch) * L_ + pos + jj]; }
            vv[j] = (f16)v;
        }
        *(f16x8*)(dst + (size_t)r * AST + cc) = vv;
    }
}

// Flat prep grid: u < WUNITS -> weight half-panels; else act tile halves. Launched with
// WUNITS blocks (fallback, weights only) or WUNITS+AUNITS (PRE path).
__global__ __launch_bounds__(256) void prep_all(
    const float* __restrict__ w0, const float* __restrict__ w1, const float* __restrict__ w2,
    const float* __restrict__ w3, const float* __restrict__ w4,
    const float* __restrict__ x, f16* __restrict__ ws) {
    __shared__ f16 wl[86 * 87];
    const int tid = threadIdx.x, u = blockIdx.x;
    if (u < WUNITS) {
        const int k = (u >> 1) & 63, h = u & 1;
        switch (u >> 7) {
            case 0: prep_one_half<0>(w0, ws, wl, k, h, tid); break;
            case 1: prep_one_half<1>(w1, ws, wl, k, h, tid); break;
            case 2: prep_one_half<2>(w2, ws, wl, k, h, tid); break;
            case 3: prep_one_half<3>(w3, ws, wl, k, h, tid); break;
            default: prep_one_half<4>(w4, ws, wl, k, h, tid); break;
        }
    } else {
        const int v = u - WUNITS;
        prep_act_half(x, ws + ACT_WS, v >> 1, v & 1, tid);
    }
}

// R16: __launch_bounds__(TPB,5) — 5 blocks/CU (LDS 5x28800=144000 <= 160K; VGPR 52 well under
// the ~96 cap). R12 showed occupancy is the dominant lever for this latency/issue-bound
// kernel; the 5th resident block costs nothing. Pipeline math unchanged from validated R13.
template<bool PRE>
__global__ __launch_bounds__(TPB, 5) void mlp_main(
    const float* __restrict__ x,
    const float* __restrict__ b0, const float* __restrict__ b1, const float* __restrict__ b2,
    const float* __restrict__ b3, const float* __restrict__ b4,
    const float* __restrict__ hw, const float* __restrict__ hb,
    const f16* __restrict__ ws, float* __restrict__ out) {
    extern __shared__ char smemraw[];
    f16*   act   = (f16*)smemraw;                 // [128 pos][AST]
    float* biasl = (float*)(act + ACT_EL);        // 5 layers x 96 padded biases, fp32
    float* headl = biasl + 480;                   // 64 padded head weights, fp32

    const int tid = threadIdx.x, k = blockIdx.x, mblk = blockIdx.y;
    const int wv = tid >> 6, lane = tid & 63, li = lane & 15, q = lane >> 4;
    const int base = mblk * MTB;
    f16* actw = act + (wv * 32) * AST;            // this wave's 32 position rows
    const f16* wk = ws + (size_t)k * 96 * AST;    // k's weight panel base (per-layer via WOFF)

    f16x8 ap[6];
    pre_a<5>(wk + WOFF[0], ap, li, q);            // L0 ks=0 frags hide under the staging

    // biases (padded to 96, fp32) + head weights into LDS
    for (int i = tid; i < 480; i += TPB) {
        int l = i / 96, e = i - l * 96;
        const float* bg = (l == 0) ? b0 : (l == 1) ? b1 : (l == 2) ? b2 : (l == 3) ? b3 : b4;
        int DO = (l == 0) ? 72 : (l == 1) ? 86 : (l == 2) ? 86 : (l == 3) ? 71 : 59;
        biasl[i] = (e < DO) ? bg[k * DO + e] : 0.f;
    }
    if (tid < 64) headl[tid] = (tid < 59) ? hw[tid] : 0.f;

    if constexpr (PRE) {
        // direct global->LDS copy of the precomputed tile: 26624 B = 26 x (64 lanes x 16 B).
        // LDS dest is wave-uniform base (+lane*16 by HW); global src is per-lane.
        const f16* src = ws + ACT_WS + (size_t)mblk * ACT_EL;
        for (int c = wv; c < 26; c += 4) {
            __builtin_amdgcn_global_load_lds(
                (const __attribute__((address_space(1))) void*)(src + c * 512 + lane * 8),
                (__attribute__((address_space(3))) void*)(act + c * 512), 16, 0, 0);
        }
    } else {
        // fallback (ws too small): in-kernel gather, R0 form.
        const int b0i = base / NOUT;
        const int thr = (b0i + 1) * NOUT;
        for (int i = tid; i < 64 * MTB; i += TPB) {
            int d = i >> 7, r = i & (MTB - 1);
            int p = base + r; if (p > NPOS - 1) p = NPOS - 1;
            int b = (p >= thr) ? b0i + 1 : b0i;
            int pos = p - b * NOUT;
            float v = 0.f;
            if (d < 60) { int c = d / 15, j = d - c * 15; v = x[(size_t)(b * C_ + c) * L_ + pos + j]; }
            act[r * AST + d] = (f16)v;
        }
        for (int i = tid; i < MTB * 2; i += TPB) {
            int r = i >> 1, cc = (i & 1) << 3;
            *(f16x8*)(act + r * AST + 80 + cc) = f16x8{0,0,0,0,0,0,0,0};
        }
    }
    const float hb0 = hb[0];
    __syncthreads();     // the ONLY barrier (also drains vmcnt for the global_load_lds copy)

    f32x4 acc[6][2];
    f32x4 (&acc5)[5][2] = reinterpret_cast<f32x4 (&)[5][2]>(acc);

    layer_mm_p<2, 5>(actw, wk + WOFF[0], ap, acc5, biasl + 0 * 96, li, q);  // L0: K=64, DO=72
    pre_a<6>(wk + WOFF[1], ap, li, q);                        // W1 ks=0 under L0 epilogue
    epilogue<5>(acc5, actw, li, q);
    layer_mm_p<3, 6>(actw, wk + WOFF[1], ap, acc, biasl + 1 * 96, li, q);   // L1: K=96(72), DO=86
    pre_a<6>(wk + WOFF[2], ap, li, q);
    epilogue<6>(acc, actw, li, q);
    layer_mm_p<3, 6>(actw, wk + WOFF[2], ap, acc, biasl + 2 * 96, li, q);   // L2: K=96(86), DO=86
    pre_a<5>(wk + WOFF[3], ap, li, q);
    epilogue<6>(acc, actw, li, q);
    layer_mm_p<3, 5>(actw, wk + WOFF[3], ap, acc5, biasl + 3 * 96, li, q);  // L3: K=96(86), DO=71
    pre_a<4>(wk + WOFF[4], ap, li, q);
    epilogue<5>(acc5, actw, li, q);
    // after L3: cols 80..95 hold stale L2 outputs — harmless: W4^T cols d>=71 are zero.

    // L4 + fused head: e 0..63 (4 m-tiles), fp32 gelu dot hw, butterfly over q
    f32x4 acc4[4][2];
    layer_mm_p<3, 4>(actw, wk + WOFF[4], ap, acc4, biasl + 4 * 96, li, q);
    float sum[2] = {0.f, 0.f};
#pragma unroll
    for (int mt = 0; mt < 4; mt++) {
        const int eb = mt * 16 + q * 4;
        f32x4 hh = *(const f32x4*)(headl + eb);
#pragma unroll
        for (int nt = 0; nt < 2; nt++) {
#pragma unroll
            for (int r = 0; r < 4; r++)
                sum[nt] += gelu_f(acc4[mt][nt][r]) * hh[r];
        }
    }
#pragma unroll
    for (int nt = 0; nt < 2; nt++) {
        float s = sum[nt];
        s += __shfl_xor(s, 16);
        s += __shfl_xor(s, 32);
        s += hb0;
        if (lane < 16) {
            int p = base + wv * 32 + nt * 16 + lane;
            if (p < NPOS) {
                int b = p / NOUT, pos = p - b * NOUT;
                out[((size_t)(b * K_ + k)) * NOUT + pos] = s;
            }
        }
    }
}

extern "C" void kernel_launch(void* const* d_in, const int* in_sizes, int n_in,
                              void* d_out, int out_size, void* d_ws, size_t ws_size,
                              hipStream_t stream) {
    const float* x  = (const float*)d_in[0];
    const float* w0 = (const float*)d_in[1];  const float* b0 = (const float*)d_in[2];
    const float* w1 = (const float*)d_in[3];  const float* b1 = (const float*)d_in[4];
    const float* w2 = (const float*)d_in[5];  const float* b2 = (const float*)d_in[6];
    const float* w3 = (const float*)d_in[7];  const float* b3 = (const float*)d_in[8];
    const float* w4 = (const float*)d_in[9];  const float* b4 = (const float*)d_in[10];
    const float* hw = (const float*)d_in[11]; const float* hb = (const float*)d_in[12];
    float* out = (float*)d_out;
    f16* ws = (f16*)d_ws;

    const bool pre = (ws_size >= WS_NEED);     // 9.69 MB: weights 6.39 + act tiles 3.30

    if (pre) {
        (void)hipFuncSetAttribute((const void*)mlp_main<true>,
                                  hipFuncAttributeMaxDynamicSharedMemorySize, (int)SMEM_BYTES);
        prep_all<<<dim3(WUNITS + AUNITS), 256, 0, stream>>>(w0, w1, w2, w3, w4, x, ws);
        // grid x=k: linear id = k + 64*m -> XCD = k%8: all m-blocks of a k share one XCD's L2,
        // and all k-blocks of one m dispatch together (act tile stays L2-hot). This dispatch-
        // order locality is load-bearing (R15 lesson).
        mlp_main<true><<<dim3(K_, NBLK), TPB, SMEM_BYTES, stream>>>(
            x, b0, b1, b2, b3, b4, hw, hb, ws, out);
    } else {
        (void)hipFuncSetAttribute((const void*)mlp_main<false>,
                                  hipFuncAttributeMaxDynamicSharedMemorySize, (int)SMEM_BYTES);
        prep_all<<<dim3(WUNITS), 256, 0, stream>>>(w0, w1, w2, w3, w4, x, ws);
        mlp_main<false><<<dim3(K_, NBLK), TPB, SMEM_BYTES, stream>>>(
            x, b0, b1, b2, b3, b4, hw, hb, ws, out);
    }
}